// Round 1
// baseline (662.334 us; speedup 1.0000x reference)
//
#include <hip/hip_runtime.h>
#include <math.h>

#define B_ROWS 4096
#define C_COLS 16000
#define NTH 10
#define ROWF4 (C_COLS / 4)   // 4000 float4 per row
static_assert((B_ROWS & (B_ROWS - 1)) == 0, "B pow2");
static_assert((C_COLS & 3) == 0, "C % 4");

__device__ __forceinline__ void block_sum2(float& a, float& b) {
#pragma unroll
  for (int off = 32; off > 0; off >>= 1) {
    a += __shfl_down(a, off);
    b += __shfl_down(b, off);
  }
  __shared__ float sa[4], sb[4];
  const int w = threadIdx.x >> 6;
  if ((threadIdx.x & 63) == 0) { sa[w] = a; sb[w] = b; }
  __syncthreads();
  if (threadIdx.x == 0) {
    a = sa[0] + sa[1] + sa[2] + sa[3];
    b = sb[0] + sb[1] + sb[2] + sb[3];
  }
}

// ---------------- K1: per-row pass over z_s and z_t ----------------
// Per row: argmax index, sum of exp(z), and for i in [0,10): count of
// elements strictly below z[row][i] (== ascending stable-argsort position).
// Also performs the distributed zeroing of colacc+acc (replaces memset).
__global__ __launch_bounds__(256) void k_rowpass(
    const float* __restrict__ zs, const float* __restrict__ zt,
    float* __restrict__ rinv, int* __restrict__ jmax, int* __restrict__ pos,
    float* __restrict__ zero_region)
{
  const int bid = blockIdx.x;

  // zero colacc (5*C) + acc (4): 80004 floats over 8192 blocks, 10 each
  if (threadIdx.x < NTH) {
    const int idx = bid * NTH + (int)threadIdx.x;
    if (idx < 5 * C_COLS + 4) zero_region[idx] = 0.f;
  }

  const int m = bid >> 12;            // 0 = student, 1 = teacher
  const int r = bid & (B_ROWS - 1);
  const float* __restrict__ z = (m ? zt : zs) + (size_t)r * C_COLS;

  // thresholds are row-uniform -> SGPRs (frees VGPRs, s-src compares)
  float th[NTH];
#pragma unroll
  for (int i = 0; i < NTH; ++i)
    th[i] = __int_as_float(__builtin_amdgcn_readfirstlane(__float_as_int(z[i])));

  int cnt[NTH];
#pragma unroll
  for (int i = 0; i < NTH; ++i) cnt[i] = 0;

  // 4 independent (value, iteration) argmax chains; 4 exp-sum accumulators
  float vmax[4]; int vit[4]; float se[4];
#pragma unroll
  for (int u = 0; u < 4; ++u) { vmax[u] = -__builtin_inff(); vit[u] = 0; se[u] = 0.f; }

  const float4* __restrict__ z4 = (const float4*)z;

  auto body = [&](const float4 v, const int itv) {
    const float xs[4] = {v.x, v.y, v.z, v.w};
#pragma unroll
    for (int i = 0; i < NTH; ++i)
      cnt[i] += (int)(xs[0] < th[i]) + (int)(xs[1] < th[i]) +
                (int)(xs[2] < th[i]) + (int)(xs[3] < th[i]);
#pragma unroll
    for (int u = 0; u < 4; ++u) {
      se[u] += __expf(xs[u]);
      if (xs[u] > vmax[u]) { vmax[u] = xs[u]; vit[u] = itv; }  // strict > keeps first
    }
  };

  // 15 or 16 iterations per thread; 1-deep prefetch of next float4
  const int iters = (ROWF4 >> 8) + ((threadIdx.x < (ROWF4 & 255)) ? 1 : 0);
  int it = threadIdx.x;
  float4 cur = z4[it];
  for (int k = 1; k < iters; ++k) {
    const float4 nxt = z4[it + 256];
    body(cur, it);
    it += 256;
    cur = nxt;
  }
  body(cur, it);

  // merge the 4 chains (column index = it*4 + u; ties -> lowest column)
  float sume = (se[0] + se[1]) + (se[2] + se[3]);
  float bmax = vmax[0];
  int bidx = vit[0] * 4 + 0;
#pragma unroll
  for (int u = 1; u < 4; ++u) {
    const int idx = vit[u] * 4 + u;
    if (vmax[u] > bmax || (vmax[u] == bmax && idx < bidx)) { bmax = vmax[u]; bidx = idx; }
  }

  // wave64 reduce
#pragma unroll
  for (int off = 32; off > 0; off >>= 1) {
    sume += __shfl_down(sume, off);
#pragma unroll
    for (int i = 0; i < NTH; ++i) cnt[i] += __shfl_down(cnt[i], off);
    const float ov = __shfl_down(bmax, off);
    const int oi = __shfl_down(bidx, off);
    if (ov > bmax || (ov == bmax && oi < bidx)) { bmax = ov; bidx = oi; }
  }
  __shared__ float s_sum[4], s_max[4];
  __shared__ int s_idx[4], s_cnt[4][NTH];
  const int wave = threadIdx.x >> 6;
  if ((threadIdx.x & 63) == 0) {
    s_sum[wave] = sume; s_max[wave] = bmax; s_idx[wave] = bidx;
#pragma unroll
    for (int i = 0; i < NTH; ++i) s_cnt[wave][i] = cnt[i];
  }
  __syncthreads();
  if (threadIdx.x == 0) {
    float ts = 0.f, tm = s_max[0];
    int ti = s_idx[0];
    int tc[NTH];
#pragma unroll
    for (int i = 0; i < NTH; ++i) tc[i] = 0;
    for (int w = 0; w < 4; ++w) {
      ts += s_sum[w];
      if (s_max[w] > tm || (s_max[w] == tm && s_idx[w] < ti)) { tm = s_max[w]; ti = s_idx[w]; }
#pragma unroll
      for (int i = 0; i < NTH; ++i) tc[i] += s_cnt[w][i];
    }
    const int base = m * B_ROWS + r;
    rinv[base] = 1.f / ts;
    jmax[base] = ti;
#pragma unroll
    for (int i = 0; i < NTH; ++i) {
      int p = tc[i];
      // stable argsort tie-break among the 10 threshold elements themselves
      for (int k = 0; k < i; ++k) p += (th[k] == th[i]) ? 1 : 0;
      pos[base * NTH + i] = p;
    }
  }
}

// ---------------- K2: inter-class (sparse closed-form pearson) ----------------
// Fully unrolled, flag-based (no runtime-indexed arrays -> no scratch).
__global__ __launch_bounds__(256) void k_inter(
    const int* __restrict__ jmax, const int* __restrict__ pos,
    float* __restrict__ acc)
{
  const int r = blockIdx.x * 256 + threadIdx.x;
  float pear = 0.f, eq = 0.f;
  if (r < B_ROWS) {
    const int js = jmax[r];
    const int jt = jmax[B_ROWS + r];
    eq = (js == jt) ? 1.f : 0.f;
    bool as[NTH], at[NTH];
    int qs[NTH], qt[NTH];
    float sds = 0.f, sds2 = 0.f, sdt = 0.f, sdt2 = 0.f;
#pragma unroll
    for (int i = 0; i < NTH; ++i) {
      const float v = (float)(i - NTH);   // delta vs baseline rank 10
      const int p = pos[r * NTH + i];
      as[i] = (p != js);                   // entry at position js is deleted
      qs[i] = p - ((p > js) ? 1 : 0);
      if (as[i]) { sds += v; sds2 += v * v; }
      const int p2 = pos[(B_ROWS + r) * NTH + i];
      at[i] = (p2 != jt);
      qt[i] = p2 - ((p2 > jt) ? 1 : 0);
      if (at[i]) { sdt += v; sdt2 += v * v; }
    }
    float sprod = 0.f;
#pragma unroll
    for (int a = 0; a < NTH; ++a)
#pragma unroll
      for (int b = 0; b < NTH; ++b)
        if (as[a] && at[b] && (qs[a] == qt[b]))
          sprod += (float)((a - NTH) * (b - NTH));   // compile-time addend
    const float Cm1 = (float)(C_COLS - 1);
    const float num  = sprod - sds * sdt / Cm1;
    const float vars = sds2 - sds * sds / Cm1;
    const float vart = sdt2 - sdt * sdt / Cm1;
    pear = num / (sqrtf(fmaxf(vars, 0.f)) * sqrtf(fmaxf(vart, 0.f)) + 1e-8f);
  }
  block_sum2(pear, eq);
  if (threadIdx.x == 0) {
    atomicAdd(&acc[0], pear);
    atomicAdd(&acc[1], eq);
  }
}

// ---------------- K3: per-column softmax moments (float4 / 16B-per-lane) ----
#define RPB 64   // rows per block
__global__ __launch_bounds__(256) void k_colpass(
    const float* __restrict__ zs, const float* __restrict__ zt,
    const float* __restrict__ rinv, float* __restrict__ colacc)
{
  const int c4 = blockIdx.x * 256 + threadIdx.x;   // float4 column group
  if (c4 >= ROWF4) return;
  const int r0 = blockIdx.y * RPB;
  float s1[4] = {0,0,0,0}, s2[4] = {0,0,0,0}, t1[4] = {0,0,0,0},
        t2[4] = {0,0,0,0}, st[4] = {0,0,0,0};
  const float4* __restrict__ zs4 = (const float4*)zs;
  const float4* __restrict__ zt4 = (const float4*)zt;
  size_t off = (size_t)r0 * ROWF4 + (size_t)c4;
#pragma unroll 4
  for (int k = 0; k < RPB; ++k) {
    const float ra = rinv[r0 + k];          // uniform -> scalar load
    const float rb = rinv[B_ROWS + r0 + k];
    const float4 a4 = zs4[off];
    const float4 b4 = zt4[off];
    const float av[4] = {a4.x, a4.y, a4.z, a4.w};
    const float bv[4] = {b4.x, b4.y, b4.z, b4.w};
#pragma unroll
    for (int u = 0; u < 4; ++u) {
      const float a = __expf(av[u]) * ra;
      const float b = __expf(bv[u]) * rb;
      s1[u] += a; s2[u] += a * a;
      t1[u] += b; t2[u] += b * b;
      st[u] += a * b;
    }
    off += ROWF4;
  }
  const int c = c4 * 4;
#pragma unroll
  for (int u = 0; u < 4; ++u) {
    atomicAdd(&colacc[0 * C_COLS + c + u], s1[u]);
    atomicAdd(&colacc[1 * C_COLS + c + u], t1[u]);
    atomicAdd(&colacc[2 * C_COLS + c + u], s2[u]);
    atomicAdd(&colacc[3 * C_COLS + c + u], t2[u]);
    atomicAdd(&colacc[4 * C_COLS + c + u], st[u]);
  }
}

// ---------------- K4: per-column pearson + reduce ----------------
__global__ __launch_bounds__(256) void k_intra(
    const float* __restrict__ colacc, float* __restrict__ acc)
{
  const int c = blockIdx.x * 256 + threadIdx.x;
  float pear = 0.f, dummy = 0.f;
  if (c < C_COLS) {
    const float s1 = colacc[0 * C_COLS + c];
    const float t1 = colacc[1 * C_COLS + c];
    const float s2 = colacc[2 * C_COLS + c];
    const float t2 = colacc[3 * C_COLS + c];
    const float st = colacc[4 * C_COLS + c];
    const float Bf = (float)B_ROWS;
    const float num = st - s1 * t1 / Bf;
    const float vs = fmaxf(s2 - s1 * s1 / Bf, 0.f);
    const float vt = fmaxf(t2 - t1 * t1 / Bf, 0.f);
    pear = num / (sqrtf(vs) * sqrtf(vt) + 1e-8f);
  }
  block_sum2(pear, dummy);
  if (threadIdx.x == 0) atomicAdd(&acc[2], pear);
}

// ---------------- K5: final scalar ----------------
__global__ void k_final(const float* __restrict__ acc, float* __restrict__ out)
{
  if (threadIdx.x == 0) {
    const float spearman = acc[0] / (float)B_ROWS;
    const float eq = acc[1] / (float)B_ROWS;
    const float inter = 1.f - (eq + spearman);   // TAU^2 = 1
    const float intra = 1.f - acc[2] / (float)C_COLS;
    out[0] = inter + intra;                      // BETA = GAMMA = 1
  }
}

extern "C" void kernel_launch(void* const* d_in, const int* in_sizes, int n_in,
                              void* d_out, int out_size, void* d_ws, size_t ws_size,
                              hipStream_t stream) {
  const float* zs = (const float*)d_in[0];
  const float* zt = (const float*)d_in[1];
  float* out = (float*)d_out;
  float* ws = (float*)d_ws;

  // workspace layout (floats):
  float* rinv   = ws;                         // 2*B = 8192
  int*   jmax   = (int*)(ws + 8192);          // 2*B = 8192
  int*   pos    = (int*)(ws + 16384);         // 2*B*10 = 81920
  float* colacc = ws + 16384 + 81920;         // 5*C = 80000
  // acc = colacc + 5*C_COLS                  // 4 scalars (zeroed with colacc)
  float* acc    = colacc + 5 * C_COLS;

  k_rowpass<<<2 * B_ROWS, 256, 0, stream>>>(zs, zt, rinv, jmax, pos, colacc);
  k_inter<<<B_ROWS / 256, 256, 0, stream>>>(jmax, pos, acc);
  dim3 g3((ROWF4 + 255) / 256, B_ROWS / RPB);
  k_colpass<<<g3, 256, 0, stream>>>(zs, zt, rinv, colacc);
  k_intra<<<(C_COLS + 255) / 256, 256, 0, stream>>>(colacc, acc);
  k_final<<<1, 64, 0, stream>>>(acc, out);
}